// Round 1
// baseline (669.104 us; speedup 1.0000x reference)
//
#include <hip/hip_runtime.h>

#define B_SZ 4096
#define D_SZ 128
#define K_SZ 256

constexpr float INV_T   = 1.0f / 0.07f;
constexpr float NOISE   = 255.0f / 1000000.0f;   // (K-1)/N
constexpr float EPS_C   = 1e-7f;
constexpr float K_OVER_N = 256.0f / 1000000.0f;  // K/N

// One block per batch row b. 256 threads = 4 waves of 64.
// Wave w computes logits for k in [w*64, w*64+64).
__global__ __launch_bounds__(256, 8) void nce_main(
    const float* __restrict__ x,        // [B, D]
    const int*   __restrict__ targets,  // [B]
    const float* __restrict__ memory,   // [N, D]
    const int*   __restrict__ indices,  // [B, K]
    float*       __restrict__ partial)  // [B]
{
    __shared__ float s_e[K_SZ];
    __shared__ float s_red[4];

    const int b    = blockIdx.x;
    const int tid  = threadIdx.x;
    const int lane = tid & 63;
    const int wave = tid >> 6;

    // lane i holds x[b, 2i] and x[b, 2i+1]
    const float2 xv = ((const float2*)(x + (size_t)b * D_SZ))[lane];

    // preload this lane's k index (col 0 overwritten with the positive)
    const int myk = wave * 64 + lane;
    const int myidx = (myk == 0) ? targets[b]
                                 : indices[(size_t)b * K_SZ + myk];

    #pragma unroll 4
    for (int j = 0; j < 64; ++j) {
        const int row = __shfl(myidx, j, 64);
        const float2 wv = ((const float2*)(memory + (size_t)row * D_SZ))[lane];
        float p = fmaf(wv.x, xv.x, wv.y * xv.y);
        // full-wave sum (64 lanes)
        #pragma unroll
        for (int m = 32; m >= 1; m >>= 1)
            p += __shfl_xor(p, m, 64);
        if (lane == j)
            s_e[wave * 64 + j] = expf(p * INV_T);
    }
    __syncthreads();

    // block reduce: S = sum_k exp(logit_k)
    const float e = s_e[tid];
    float sum = e;
    #pragma unroll
    for (int m = 32; m >= 1; m >>= 1)
        sum += __shfl_xor(sum, m, 64);
    if (lane == 0) s_red[wave] = sum;
    __syncthreads();
    const float S = s_red[0] + s_red[1] + s_red[2] + s_red[3];

    // sims_k = e_k / S * (K/N)
    const float sims = e * (K_OVER_N / S);
    float term;
    if (tid == 0)
        term = logf(sims / (sims + NOISE + EPS_C));   // lnPmt (positive)
    else
        term = logf(NOISE / (sims + NOISE + EPS_C));  // lnPon (noise)

    float t = term;
    #pragma unroll
    for (int m = 32; m >= 1; m >>= 1)
        t += __shfl_xor(t, m, 64);
    __syncthreads();   // all reads of s_red done before re-use
    if (lane == 0) s_red[wave] = t;
    __syncthreads();
    if (tid == 0)
        partial[b] = s_red[0] + s_red[1] + s_red[2] + s_red[3];
}

// Single-block reduction of the 4096 per-row partials.
__global__ __launch_bounds__(256) void nce_final(
    const float* __restrict__ partial, float* __restrict__ out)
{
    const int tid = threadIdx.x;
    float s = 0.0f;
    #pragma unroll
    for (int i = tid; i < B_SZ; i += 256)
        s += partial[i];
    #pragma unroll
    for (int m = 32; m >= 1; m >>= 1)
        s += __shfl_xor(s, m, 64);
    __shared__ float sr[4];
    if ((tid & 63) == 0) sr[tid >> 6] = s;
    __syncthreads();
    if (tid == 0)
        out[0] = -(sr[0] + sr[1] + sr[2] + sr[3]) / (float)B_SZ;
}

extern "C" void kernel_launch(void* const* d_in, const int* in_sizes, int n_in,
                              void* d_out, int out_size, void* d_ws, size_t ws_size,
                              hipStream_t stream) {
    const float* x       = (const float*)d_in[0];
    const int*   targets = (const int*)  d_in[1];
    const float* memory  = (const float*)d_in[2];
    const int*   indices = (const int*)  d_in[3];
    float* out     = (float*)d_out;
    float* partial = (float*)d_ws;   // B floats of scratch

    nce_main<<<B_SZ, 256, 0, stream>>>(x, targets, memory, indices, partial);
    nce_final<<<1, 256, 0, stream>>>(partial, out);
}

// Round 2
// 640.961 us; speedup vs baseline: 1.0439x; 1.0439x over previous
//
#include <hip/hip_runtime.h>

#define B_SZ 4096
#define D_SZ 128
#define K_SZ 256

constexpr float INV_T    = 1.0f / 0.07f;
constexpr float NOISE    = 255.0f / 1000000.0f;   // (K-1)/N
constexpr float EPS_C    = 1e-7f;
constexpr float K_OVER_N = 256.0f / 1000000.0f;   // K/N

// One block per batch row b. 256 threads = 4 waves of 64.
// Wave w computes logits for k in [w*64, w*64+64), 2 rows per iteration:
// lanes 0-31 do row 2*it, lanes 32-63 do row 2*it+1. Each lane loads one
// float4 (16 B) -> 1024 B per wave load instruction (full coalescing).
__global__ __launch_bounds__(256, 8) void nce_main(
    const float* __restrict__ x,        // [B, D]
    const int*   __restrict__ targets,  // [B]
    const float* __restrict__ memory,   // [N, D]
    const int*   __restrict__ indices,  // [B, K]
    float*       __restrict__ partial)  // [B]
{
    __shared__ float s_e[K_SZ];
    __shared__ float s_red[4];

    const int b    = blockIdx.x;
    const int tid  = threadIdx.x;
    const int lane = tid & 63;
    const int wave = tid >> 6;
    const int sub  = lane & 31;   // float4 slot within the row
    const int half = lane >> 5;   // which of the 2 rows this lane serves

    // lane covers x[b, 4*sub .. 4*sub+3]
    const float4 xv = ((const float4*)(x + (size_t)b * D_SZ))[sub];

    // this lane's k index (col 0 overwritten with the positive target)
    const int myk = wave * 64 + lane;
    const int myidx = (myk == 0) ? targets[b]
                                 : indices[(size_t)b * K_SZ + myk];

    #pragma unroll 4
    for (int it = 0; it < 32; ++it) {
        const int kk  = it * 2 + half;
        const int row = __shfl(myidx, kk, 64);   // broadcast sampled row id
        const float4 wv = ((const float4*)(memory + (size_t)row * D_SZ))[sub];
        float p = fmaf(wv.x, xv.x, fmaf(wv.y, xv.y,
                  fmaf(wv.z, xv.z, wv.w * xv.w)));
        // reduce within each 32-lane half (masks < 32 never cross halves)
        #pragma unroll
        for (int m = 16; m >= 1; m >>= 1)
            p += __shfl_xor(p, m, 64);
        if (sub == 0)
            s_e[wave * 64 + kk] = expf(p * INV_T);
    }
    __syncthreads();

    // block reduce: S = sum_k exp(logit_k)
    const float e = s_e[tid];
    float sum = e;
    #pragma unroll
    for (int m = 32; m >= 1; m >>= 1)
        sum += __shfl_xor(sum, m, 64);
    if (lane == 0) s_red[wave] = sum;
    __syncthreads();
    const float S = s_red[0] + s_red[1] + s_red[2] + s_red[3];

    // sims_k = e_k / S * (K/N)
    const float sims = e * (K_OVER_N / S);
    float term;
    if (tid == 0)
        term = logf(sims / (sims + NOISE + EPS_C));   // lnPmt (positive)
    else
        term = logf(NOISE / (sims + NOISE + EPS_C));  // lnPon (noise)

    float t = term;
    #pragma unroll
    for (int m = 32; m >= 1; m >>= 1)
        t += __shfl_xor(t, m, 64);
    __syncthreads();   // all reads of s_red done before re-use
    if (lane == 0) s_red[wave] = t;
    __syncthreads();
    if (tid == 0)
        partial[b] = s_red[0] + s_red[1] + s_red[2] + s_red[3];
}

// Single-block reduction of the 4096 per-row partials.
__global__ __launch_bounds__(256) void nce_final(
    const float* __restrict__ partial, float* __restrict__ out)
{
    const int tid = threadIdx.x;
    float s = 0.0f;
    #pragma unroll
    for (int i = tid; i < B_SZ; i += 256)
        s += partial[i];
    #pragma unroll
    for (int m = 32; m >= 1; m >>= 1)
        s += __shfl_xor(s, m, 64);
    __shared__ float sr[4];
    if ((tid & 63) == 0) sr[tid >> 6] = s;
    __syncthreads();
    if (tid == 0)
        out[0] = -(sr[0] + sr[1] + sr[2] + sr[3]) / (float)B_SZ;
}

extern "C" void kernel_launch(void* const* d_in, const int* in_sizes, int n_in,
                              void* d_out, int out_size, void* d_ws, size_t ws_size,
                              hipStream_t stream) {
    const float* x       = (const float*)d_in[0];
    const int*   targets = (const int*)  d_in[1];
    const float* memory  = (const float*)d_in[2];
    const int*   indices = (const int*)  d_in[3];
    float* out     = (float*)d_out;
    float* partial = (float*)d_ws;   // B floats of scratch

    nce_main<<<B_SZ, 256, 0, stream>>>(x, targets, memory, indices, partial);
    nce_final<<<1, 256, 0, stream>>>(partial, out);
}